// Round 8
// baseline (819.908 us; speedup 1.0000x reference)
//
#include <hip/hip_runtime.h>

typedef __attribute__((ext_vector_type(8))) unsigned short u16x8;
typedef __attribute__((ext_vector_type(8))) short s16x8;
typedef __attribute__((ext_vector_type(4))) float f32x4;
typedef __attribute__((ext_vector_type(2))) unsigned int u32x2;

#define D_MODEL 1024
#define NROWS 32768
#define BK 64
#define NT 16  // K-tiles = 1024/64

__device__ __forceinline__ unsigned short f2bf(float f) {
  union { float f; unsigned int u; } c; c.f = f;
  return (unsigned short)((c.u + 0x7fffu + ((c.u >> 16) & 1u)) >> 16);
}
__device__ __forceinline__ float bf2f(unsigned short h) {
  union { unsigned int u; float f; } c; c.u = ((unsigned int)h) << 16;
  return c.f;
}
// packed fp32 pair -> 2x bf16 (RTNE); lo -> low 16b, hi -> high 16b (HW-verified in R5)
__device__ __forceinline__ unsigned int cvtpk_bf16(float lo, float hi) {
  unsigned int r;
  asm("v_cvt_pk_bf16_f32 %0, %1, %2" : "=v"(r) : "v"(lo), "v"(hi));
  return r;
}

// async global->LDS, 16B per lane; lds dest is wave-uniform base (+lane*16 implicit)
__device__ __forceinline__ void gload_lds16(const void* gsrc, void* ldst) {
  const __attribute__((address_space(1))) void* g =
      reinterpret_cast<const __attribute__((address_space(1))) void*>(
          reinterpret_cast<unsigned long long>(gsrc));
  __attribute__((address_space(3))) void* l =
      reinterpret_cast<__attribute__((address_space(3))) void*>(
          static_cast<unsigned int>(reinterpret_cast<unsigned long long>(ldst)));
  __builtin_amdgcn_global_load_lds(g, l, 16, 0, 0);
}

#define BAR() asm volatile("s_barrier" ::: "memory")

// ---------- weight transpose + convert: W (1024x1024 fp32, KxN) -> WT (NxK bf16) ----------
__global__ __launch_bounds__(256) void wtrans_kernel(
    const float* __restrict__ W0, const float* __restrict__ W1,
    const float* __restrict__ W2, const float* __restrict__ W3,
    unsigned short* __restrict__ T0, unsigned short* __restrict__ T1,
    unsigned short* __restrict__ T2, unsigned short* __restrict__ T3) {
  const float* W = blockIdx.z == 0 ? W0 : blockIdx.z == 1 ? W1 : blockIdx.z == 2 ? W2 : W3;
  unsigned short* T = blockIdx.z == 0 ? T0 : blockIdx.z == 1 ? T1 : blockIdx.z == 2 ? T2 : T3;
  __shared__ float tile[32][33];
  const int tx = threadIdx.x & 31, ty = threadIdx.x >> 5;
  const int n0 = blockIdx.x * 32, k0 = blockIdx.y * 32;
#pragma unroll
  for (int i = 0; i < 4; ++i)
    tile[ty + 8 * i][tx] = W[(size_t)(k0 + ty + 8 * i) * D_MODEL + n0 + tx];
  __syncthreads();
#pragma unroll
  for (int i = 0; i < 4; ++i)
    T[(size_t)(n0 + ty + 8 * i) * D_MODEL + k0 + tx] = f2bf(tile[tx][ty + 8 * i]);
}

#define MFMA16(p, A00, A01, A10, A11)                                                        \
  _Pragma("unroll") for (int n = 0; n < 4; ++n) {                                            \
    acc[2*(p)][n]   = __builtin_amdgcn_mfma_f32_16x16x32_bf16(A00, bfr[n][0], acc[2*(p)][n], 0, 0, 0);   \
    acc[2*(p)][n]   = __builtin_amdgcn_mfma_f32_16x16x32_bf16(A01, bfr[n][1], acc[2*(p)][n], 0, 0, 0);   \
    acc[2*(p)+1][n] = __builtin_amdgcn_mfma_f32_16x16x32_bf16(A10, bfr[n][0], acc[2*(p)+1][n], 0, 0, 0); \
    acc[2*(p)+1][n] = __builtin_amdgcn_mfma_f32_16x16x32_bf16(A11, bfr[n][1], acc[2*(p)+1][n], 0, 0, 0); \
  }

#define LDA_(Ac, m, ksoff) (*(const s16x8*)((Ac) + (wm * 128 + (m) * 16 + lrow) * 128 + (ksoff)))
#define LDB_(Bc, n, ksoff) (*(const s16x8*)((Bc) + (wn * 64 + (n) * 16 + lrow) * 128 + (ksoff)))

// =====================================================================================
// qkv fused kernel: 8 compute waves (R2-proven schedule, B-only vmcnt(4) ledger) +
// 4 producer waves (fp32 A -> cvt_pk -> swizzled ds_write, per-wave private vmcnt).
// A triple-buffered (3x32KB), B double-buffered (2x32KB) = 160KB LDS. Producers write
// A(u+1) -> buffer (u+1)%3 during tile u (ph2/ph3), lgkmcnt(0) before the last barrier;
// compute reads A(u) from buffer u%3. Barrier count per path: 1 + 16*8 (verified equal).
// Producer reg sets S0/S1 are static-indexed via unroll-2 tile macro (rule #20).
// =====================================================================================

// producer: load 8 row-chunks of A(u+2) into set S (k0 half)
#define PLOAD(S, u, k0)                                                                   \
  _Pragma("unroll") for (int k = (k0); k < (k0) + 8; ++k)                                 \
    S[k] = *(const f32x4*)(Abase + (size_t)(16 * k) * D_MODEL + (size_t)(u) * BK);

// producer: cvt + swizzled ds_write of 8 chunks from set S into LDS buffer `dst`
#define PWRITE(S, dst, k0)                                                                \
  _Pragma("unroll") for (int k = (k0); k < (k0) + 8; ++k) {                               \
    const int r = pr + 16 * k;                                                            \
    u32x2 wv;                                                                             \
    wv[0] = cvtpk_bf16(S[k][0], S[k][1]);                                                 \
    wv[1] = cvtpk_bf16(S[k][2], S[k][3]);                                                 \
    *(u32x2*)((dst) + (r >> 7) * 16384 + (r & 127) * 128 +                                \
              (((pc >> 1) ^ (r & 7)) * 16) + (pc & 1) * 8) = wv;                          \
  }

// one producer tile: loads A(u+2)->SL, writes A(u+1)<-SW into Pnxt; 8 barriers
#define PROD_TILE(u, SL, SW)                                                              \
  {                                                                                       \
    const bool ld = ((u) + 2 < NT);                                                       \
    const bool wr = ((u) + 1 < NT);                                                       \
    if (ld) { PLOAD(SL, (u) + 2, 0) }                                                     \
    BAR(); BAR();                                                                         \
    if (ld) { PLOAD(SL, (u) + 2, 8) }                                                     \
    BAR(); BAR();                                                                         \
    if (wr) { PWRITE(SW, Pnxt, 0) }                                                       \
    BAR(); BAR();                                                                         \
    if (wr) { PWRITE(SW, Pnxt, 8) }                                                       \
    BAR();                                                                                \
    asm volatile("s_waitcnt lgkmcnt(0)" ::: "memory");                                    \
    BAR();                                                                                \
    char* t_ = Pcur; Pcur = Pnxt; Pnxt = Ppf; Ppf = t_;                                   \
  }

__global__ __launch_bounds__(768, 3) void qkv_gemm8p(
    const float* __restrict__ Xq, const float* __restrict__ Xk, const float* __restrict__ Xv,
    const unsigned short* __restrict__ WqT, const unsigned short* __restrict__ WkT,
    const unsigned short* __restrict__ WvT,
    const float* __restrict__ bq, const float* __restrict__ bk, const float* __restrict__ bv,
    unsigned short* __restrict__ Qb, unsigned short* __restrict__ Kb,
    unsigned short* __restrict__ Vb) {
  extern __shared__ char smem[];
  const int z = blockIdx.z;
  const float* A32 = z == 0 ? Xq : z == 1 ? Xk : Xv;
  const unsigned short* BT = z == 0 ? WqT : z == 1 ? WkT : WvT;
  const float* bias = z == 0 ? bq : z == 1 ? bk : bv;
  unsigned short* C = z == 0 ? Qb : z == 1 ? Kb : Vb;

  const int tid = threadIdx.x;
  const int id = blockIdx.y * gridDim.x + blockIdx.x;  // 0..511
  const int sw = (id & 7) * 64 + (id >> 3);            // bijective XCD swizzle (512%8==0)
  const int mbase = (sw >> 2) * 256;
  const int nbase = (sw & 3) * 256;

  if (tid < 512) {
    // ================= compute path (R2-proven schedule; A staged by producers) ========
    const int lane = tid & 63, wid = tid >> 6;
    const int wm = wid >> 2, wn = wid & 3;
    const int lrow = lane & 15, lkg = lane >> 4;
    const int sgoff = (((tid & 7) ^ ((tid >> 3) & 7)) * 8);
    const int srow = tid >> 3;
    const int soff0 = ((0 + lkg) ^ (lrow & 7)) * 16;
    const int soff1 = ((4 + lkg) ^ (lrow & 7)) * 16;
    const int ldsw = wid * 1024;

    auto stB = [&](char* dst, int u, int half) {
      const unsigned short* G =
          BT + (size_t)(nbase + half * 128 + srow) * D_MODEL + u * BK + sgoff;
      char* L = dst + half * 16384 + ldsw;
      gload_lds16(G, L);
      gload_lds16(G + (size_t)64 * D_MODEL, L + 8192);
    };

    f32x4 acc[8][4];
    f32x4 zero = {0.f, 0.f, 0.f, 0.f};
#pragma unroll
    for (int m = 0; m < 8; ++m)
#pragma unroll
      for (int n = 0; n < 4; ++n) acc[m][n] = zero;
    s16x8 bfr[4][2];

    char* Acur = smem;            // A(u)   = buffer u%3
    char* Anxt = smem + 32768;
    char* Apf  = smem + 65536;
    char* Bcur = smem + 98304;
    char* Bnxt = smem + 131072;

    // prologue: B(0),B(1) staged; vmcnt(4) keeps B(1) in flight. A(0) by producers.
    stB(Bcur, 0, 0); stB(Bcur, 0, 1);
    stB(Bnxt, 1, 0); stB(Bnxt, 1, 1);
    asm volatile("s_waitcnt vmcnt(4)" ::: "memory");
    BAR();

#pragma unroll 1
    for (int u = 0; u < NT; ++u) {
      const bool pf = (u + 2 < NT);
      // ---- phase 0 ----
      {
        s16x8 a00 = LDA_(Acur, 0, soff0), a01 = LDA_(Acur, 0, soff1);
        s16x8 a10 = LDA_(Acur, 1, soff0), a11 = LDA_(Acur, 1, soff1);
#pragma unroll
        for (int n = 0; n < 4; ++n) { bfr[n][0] = LDB_(Bcur, n, soff0); bfr[n][1] = LDB_(Bcur, n, soff1); }
        BAR();
        __builtin_amdgcn_s_setprio(1);
        MFMA16(0, a00, a01, a10, a11);
        __builtin_amdgcn_s_setprio(0);
        BAR();
      }
      // ---- phase 1 ----
      {
        s16x8 a00 = LDA_(Acur, 2, soff0), a01 = LDA_(Acur, 2, soff1);
        s16x8 a10 = LDA_(Acur, 3, soff0), a11 = LDA_(Acur, 3, soff1);
        BAR();
        __builtin_amdgcn_s_setprio(1);
        MFMA16(1, a00, a01, a10, a11);
        __builtin_amdgcn_s_setprio(0);
        BAR();
      }
      // ---- phase 2: stage B(u+2) lo -> Bcur (reads done at ph0) ----
      {
        s16x8 a00 = LDA_(Acur, 4, soff0), a01 = LDA_(Acur, 4, soff1);
        s16x8 a10 = LDA_(Acur, 5, soff0), a11 = LDA_(Acur, 5, soff1);
        if (pf) stB(Bcur, u + 2, 0);
        BAR();
        __builtin_amdgcn_s_setprio(1);
        MFMA16(2, a00, a01, a10, a11);
        __builtin_amdgcn_s_setprio(0);
        BAR();
      }
      // ---- phase 3: stage B(u+2) hi; counted vmcnt(4) (B-only ledger) ----
      {
        s16x8 a00 = LDA_(Acur, 6, soff0), a01 = LDA_(Acur, 6, soff1);
        s16x8 a10 = LDA_(Acur, 7, soff0), a11 = LDA_(Acur, 7, soff1);
        if (pf) {
          stB(Bcur, u + 2, 1);
          asm volatile("s_waitcnt vmcnt(4)" ::: "memory");  // keep B(u+2); drain B(u+1)
        } else {
          asm volatile("s_waitcnt vmcnt(0)" ::: "memory");
        }
        BAR();
        __builtin_amdgcn_s_setprio(1);
        MFMA16(3, a00, a01, a10, a11);
        __builtin_amdgcn_s_setprio(0);
        BAR();
      }
      // rotate (register moves only — rule #20)
      char* t = Acur; Acur = Anxt; Anxt = Apf; Apf = t;
      char* tb = Bcur; Bcur = Bnxt; Bnxt = tb;
    }

    // ---- epilogue: C layout col=lane&15, row=(lane>>4)*4+r (m89-verified) ----
    const size_t crow0 = mbase + wm * 128;
    const int ccol0 = nbase + wn * 64;
#pragma unroll
    for (int m = 0; m < 8; ++m) {
#pragma unroll
      for (int n = 0; n < 4; ++n) {
        const int col = ccol0 + n * 16 + lrow;
        const float bv = bias[col];
#pragma unroll
        for (int r = 0; r < 4; ++r) {
          const size_t row = crow0 + m * 16 + lkg * 4 + r;
          C[row * D_MODEL + col] = f2bf(acc[m][n][r] + bv);
        }
      }
    }
  } else {
    // ================= producer path (4 waves, fp32 A -> bf16 LDS) =====================
    const int pt = tid - 512;      // 0..255
    const int pr = pt >> 4;        // base row 0..15 (handles rows pr+16k)
    const int pc = pt & 15;        // 16B fp32 chunk within the 64-col row (0..15)
    const float* Abase = A32 + (size_t)(mbase + pr) * D_MODEL + pc * 4;

    char* Pcur = smem;             // buffer u%3   (at tile u)
    char* Pnxt = smem + 32768;     // buffer (u+1)%3 — producer write target
    char* Ppf  = smem + 65536;

    f32x4 S0[16], S1[16];

    // prologue: A(0) -> S0 -> LDS buf0; A(1) -> S1 (written during tile 0)
    PLOAD(S0, 0, 0) PLOAD(S0, 0, 8)
    PWRITE(S0, Pcur, 0) PWRITE(S0, Pcur, 8)   // data-dep drains S0 loads (own-wave vmcnt)
    PLOAD(S1, 1, 0) PLOAD(S1, 1, 8)
    asm volatile("s_waitcnt lgkmcnt(0)" ::: "memory");
    BAR();

#pragma unroll 1
    for (int uu = 0; uu < NT; uu += 2) {
      PROD_TILE(uu, S0, S1)       // load A(uu+2)->S0, write A(uu+1)<-S1
      PROD_TILE(uu + 1, S1, S0)   // load A(uu+3)->S1, write A(uu+2)<-S0
    }
    // no epilogue for producers
  }
}

// =====================================================================================
// out_gemm8: R7-proven bf16 path (A+B via gload_lds, triple-A rotation, vmcnt(8))
// =====================================================================================
__global__ __launch_bounds__(512, 1) void out_gemm8(
    const unsigned short* __restrict__ A, const unsigned short* __restrict__ BT,
    const float* __restrict__ bias, float* __restrict__ Cp) {
  extern __shared__ char smem[];
  const int tid = threadIdx.x;
  const int lane = tid & 63, wid = tid >> 6;
  const int wm = wid >> 2, wn = wid & 3;
  const int lrow = lane & 15, lkg = lane >> 4;

  const int id = blockIdx.y * gridDim.x + blockIdx.x;
  const int sw = (id & 7) * 64 + (id >> 3);
  const int mbase = (sw >> 2) * 256;
  const int nbase = (sw & 3) * 256;

  const int sgoff = (((tid & 7) ^ ((tid >> 3) & 7)) * 8);
  const int srow = tid >> 3;
  const int soff0 = ((0 + lkg) ^ (lrow & 7)) * 16;
  const int soff1 = ((4 + lkg) ^ (lrow & 7)) * 16;
  const int ldsw = wid * 1024;

  auto stA = [&](char* dst, int u, int half) {
    const unsigned short* G =
        A + (size_t)(mbase + half * 128 + srow) * D_MODEL + u * BK + sgoff;
    char* L = dst + half * 16384 + ldsw;
    gload_lds16(G, L);
    gload_lds16(G + (size_t)64 * D_MODEL, L + 8192);
  };
  auto stB = [&](char* dst, int u, int half) {
    const unsigned short* G =
        BT + (size_t)(nbase + half * 128 + srow) * D_MODEL + u * BK + sgoff;
    char* L = dst + half * 16384 + ldsw;
    gload_lds16(G, L);
    gload_lds16(G + (size_t)64 * D_MODEL, L + 8192);
  };

  f32x4 acc[8][4];
  f32x4 zero = {0.f, 0.f, 0.f, 0.f};
#pragma unroll
  for (int m = 0; m < 8; ++m)
#pragma unroll
    for (int n = 0; n < 4; ++n) acc[m][n] = zero;
  s16x8 bfr[4][2];

  char* Acur = smem;
  char* Anxt = smem + 32768;
  char* Apf  = smem + 65536;
  char* Bcur = smem + 98304;
  char* Bnxt = smem + 131072;

  stA(Acur, 0, 0); stA(Acur, 0, 1); stB(Bcur, 0, 0); stB(Bcur, 0, 1);
  stA(Anxt, 1, 0); stA(Anxt, 1, 1); stB(Bnxt, 1, 0); stB(Bnxt, 1, 1);
  asm volatile("s_waitcnt vmcnt(8)" ::: "memory");
  BAR();

#pragma unroll 1
  for (int u = 0; u < NT; ++u) {
    const bool pf = (u + 2 < NT);
    {
      s16x8 a00 = LDA_(Acur, 0, soff0), a01 = LDA_(Acur, 0, soff1);
      s16x8 a10 = LDA_(Acur, 1, soff0), a11 = LDA_(Acur, 1, soff1);
#pragma unroll
      for (int n = 0; n < 4; ++n) { bfr[n][0] = LDB_(Bcur, n, soff0); bfr[n][1] = LDB_(Bcur, n, soff1); }
      if (pf) stA(Apf, u + 2, 0);
      BAR();
      __builtin_amdgcn_s_setprio(1);
      MFMA16(0, a00, a01, a10, a11);
      __builtin_amdgcn_s_setprio(0);
      BAR();
    }
    {
      s16x8 a00 = LDA_(Acur, 2, soff0), a01 = LDA_(Acur, 2, soff1);
      s16x8 a10 = LDA_(Acur, 3, soff0), a11 = LDA_(Acur, 3, soff1);
      if (pf) stA(Apf, u + 2, 1);
      BAR();
      __builtin_amdgcn_s_setprio(1);
      MFMA16(1, a00, a01, a10, a11);
      __builtin_amdgcn_s_setprio(0);
      BAR();
    }
    {
      s16x8 a00 = LDA_(Acur, 4, soff0), a01 = LDA_(Acur, 4, soff1);
      s16x8 a10 = LDA_(Acur, 5, soff0), a11 = LDA_(Acur, 5, soff1);
      if (pf) stB(Bcur, u + 2, 0);
      BAR();
      __builtin_amdgcn_s_setprio(1);
      MFMA16(2, a00, a01, a10, a11);
      __builtin_amdgcn_s_setprio(0);
      BAR();
    }
    {
      s16x8 a00 = LDA_(Acur, 6, soff0), a01 = LDA_(Acur, 6, soff1);
      s16x8 a10 = LDA_(Acur, 7, soff0), a11 = LDA_(Acur, 7, soff1);
      if (pf) {
        stB(Bcur, u + 2, 1);
        asm volatile("s_waitcnt vmcnt(8)" ::: "memory");
      } else {
        asm volatile("s_waitcnt vmcnt(0)" ::: "memory");
      }
      BAR();
      __builtin_amdgcn_s_setprio(1);
      MFMA16(3, a00, a01, a10, a11);
      __builtin_amdgcn_s_setprio(0);
      BAR();
    }
    char* t = Acur; Acur = Anxt; Anxt = Apf; Apf = t;
    char* tb = Bcur; Bcur = Bnxt; Bnxt = tb;
  }

  const size_t crow0 = mbase + wm * 128;
  const int ccol0 = nbase + wn * 64;
#pragma unroll
  for (int m = 0; m < 8; ++m) {
#pragma unroll
    for (int n = 0; n < 4; ++n) {
      const int col = ccol0 + n * 16 + lrow;
      const float bv = bias[col];
#pragma unroll
      for (int r = 0; r < 4; ++r) {
        const size_t row = crow0 + m * 16 + lkg * 4 + r;
        Cp[row * D_MODEL + col] = acc[m][n][r] + bv;
      }
    }
  }
}

// ---------- per-row 16-head attention: one wave per batch row ----------
__global__ __launch_bounds__(256) void attn_kernel(
    const unsigned short* __restrict__ Qb, const unsigned short* __restrict__ Kb,
    const unsigned short* __restrict__ Vb, unsigned short* __restrict__ Ob) {
  __shared__ __align__(16) unsigned short sm[4][3][16 * 72];
  const int tid = threadIdx.x, lane = tid & 63, wid = tid >> 6;
  const size_t row = (size_t)blockIdx.x * 4 + wid;
  const unsigned short* srcs[3] = {Qb + row * 1024, Kb + row * 1024, Vb + row * 1024};
#pragma unroll
  for (int m = 0; m < 3; ++m) {
#pragma unroll
    for (int i = 0; i < 2; ++i) {
      int c = lane * 2 + i;
      int h = c >> 3, col = (c & 7) * 8;
      *(u16x8*)&sm[wid][m][h * 72 + col] = *(const u16x8*)(srcs[m] + h * 64 + col);
    }
  }
  __syncthreads();

  const int h = lane & 15, gq = lane >> 4;
  float s[4] = {0.f, 0.f, 0.f, 0.f};
#pragma unroll
  for (int dc = 0; dc < 8; ++dc) {
    u16x8 qv = *(const u16x8*)&sm[wid][0][h * 72 + dc * 8];
    float qf[8];
#pragma unroll
    for (int e = 0; e < 8; ++e) qf[e] = bf2f(qv[e]);
#pragma unroll
    for (int j = 0; j < 4; ++j) {
      u16x8 kv = *(const u16x8*)&sm[wid][1][(gq * 4 + j) * 72 + dc * 8];
#pragma unroll
      for (int e = 0; e < 8; ++e) s[j] += qf[e] * bf2f(kv[e]);
    }
  }
  float mx = s[0];
#pragma unroll
  for (int j = 0; j < 4; ++j) { s[j] *= 0.125f; mx = fmaxf(mx * (j == 0 ? 0.125f : 1.f), s[j]); }
  mx = fmaxf(mx, __shfl_xor(mx, 16, 64));
  mx = fmaxf(mx, __shfl_xor(mx, 32, 64));
  float p[4], sum = 0.f;
#pragma unroll
  for (int j = 0; j < 4; ++j) { p[j] = __expf(s[j] - mx); sum += p[j]; }
  sum += __shfl_xor(sum, 16, 64);
  sum += __shfl_xor(sum, 32, 64);
  const float rinv = 1.0f / sum;
  float pall[16];
#pragma unroll
  for (int t = 0; t < 4; ++t)
#pragma unroll
    for (int j = 0; j < 4; ++j) pall[t * 4 + j] = __shfl(p[j], h + 16 * t, 64);
  float o[16];
#pragma unroll
  for (int e = 0; e < 16; ++e) o[e] = 0.f;
  const int db = gq * 16;
#pragma unroll
  for (int g = 0; g < 16; ++g) {
    float pg = pall[g];
    u16x8 v0 = *(const u16x8*)&sm[wid][2][g * 72 + db];
    u16x8 v1 = *(const u16x8*)&sm[wid][2][g * 72 + db + 8];
#pragma unroll
    for (int e = 0; e < 8; ++e) { o[e] += pg * bf2f(v0[e]); o[8 + e] += pg * bf2f(v1[e]); }
  }
  u16x8 r0, r1;
#pragma unroll
  for (int e = 0; e < 8; ++e) { r0[e] = f2bf(o[e] * rinv); r1[e] = f2bf(o[8 + e] * rinv); }
  unsigned short* dst = Ob + row * 1024 + h * 64 + db;
  *(u16x8*)dst = r0;
  *(u16x8*)(dst + 8) = r1;
}

extern "C" void kernel_launch(void* const* d_in, const int* in_sizes, int n_in,
                              void* d_out, int out_size, void* d_ws, size_t ws_size,
                              hipStream_t stream) {
  const float* queries = (const float*)d_in[0];
  const float* keys    = (const float*)d_in[1];
  const float* values  = (const float*)d_in[2];
  const float* Wq = (const float*)d_in[3];
  const float* bq = (const float*)d_in[4];
  const float* Wk = (const float*)d_in[5];
  const float* bk = (const float*)d_in[6];
  const float* Wv = (const float*)d_in[7];
  const float* bv = (const float*)d_in[8];
  const float* Wo = (const float*)d_in[9];
  const float* bo = (const float*)d_in[10];
  float* out = (float*)d_out;

  unsigned short* ws = (unsigned short*)d_ws;
  const size_t WE = (size_t)1024 * 1024;
  const size_t XE = (size_t)NROWS * 1024;
  unsigned short* WqT = ws;
  unsigned short* WkT = WqT + WE;
  unsigned short* WvT = WkT + WE;
  unsigned short* WoT = WvT + WE;
  unsigned short* Qb  = WoT + WE;
  unsigned short* Kb  = Qb + XE;
  unsigned short* Vb  = Kb + XE;
  unsigned short* Ob  = Vb + XE;
  // ws use: 8 MB weights + 4 x 64 MB = 264 MB

  hipFuncSetAttribute((const void*)qkv_gemm8p, hipFuncAttributeMaxDynamicSharedMemorySize, 163840);
  hipFuncSetAttribute((const void*)out_gemm8, hipFuncAttributeMaxDynamicSharedMemorySize, 163840);

  wtrans_kernel<<<dim3(32, 32, 4), 256, 0, stream>>>(Wq, Wk, Wv, Wo, WqT, WkT, WvT, WoT);
  qkv_gemm8p<<<dim3(4, 128, 3), 768, 163840, stream>>>(
      queries, keys, values, WqT, WkT, WvT, bq, bk, bv, Qb, Kb, Vb);
  attn_kernel<<<dim3(NROWS / 4), 256, 0, stream>>>(Qb, Kb, Vb, Ob);
  out_gemm8<<<dim3(4, 128, 1), 512, 163840, stream>>>(Ob, WoT, bo, out);
}

// Round 9
// 817.207 us; speedup vs baseline: 1.0033x; 1.0033x over previous
//
#include <hip/hip_runtime.h>

typedef __attribute__((ext_vector_type(8))) unsigned short u16x8;
typedef __attribute__((ext_vector_type(8))) short s16x8;
typedef __attribute__((ext_vector_type(4))) float f32x4;
typedef __attribute__((ext_vector_type(2))) unsigned int u32x2;

#define D_MODEL 1024
#define NROWS 32768
#define BK 64
#define NT 16  // K-tiles = 1024/64

__device__ __forceinline__ unsigned short f2bf(float f) {
  union { float f; unsigned int u; } c; c.f = f;
  return (unsigned short)((c.u + 0x7fffu + ((c.u >> 16) & 1u)) >> 16);
}
__device__ __forceinline__ float bf2f(unsigned short h) {
  union { unsigned int u; float f; } c; c.u = ((unsigned int)h) << 16;
  return c.f;
}
// packed fp32 pair -> 2x bf16 (RTNE); lo -> low 16b, hi -> high 16b (HW-verified in R5)
__device__ __forceinline__ unsigned int cvtpk_bf16(float lo, float hi) {
  unsigned int r;
  asm("v_cvt_pk_bf16_f32 %0, %1, %2" : "=v"(r) : "v"(lo), "v"(hi));
  return r;
}

// async global->LDS, 16B per lane; lds dest is wave-uniform base (+lane*16 implicit)
__device__ __forceinline__ void gload_lds16(const void* gsrc, void* ldst) {
  const __attribute__((address_space(1))) void* g =
      reinterpret_cast<const __attribute__((address_space(1))) void*>(
          reinterpret_cast<unsigned long long>(gsrc));
  __attribute__((address_space(3))) void* l =
      reinterpret_cast<__attribute__((address_space(3))) void*>(
          static_cast<unsigned int>(reinterpret_cast<unsigned long long>(ldst)));
  __builtin_amdgcn_global_load_lds(g, l, 16, 0, 0);
}

#define BAR() asm volatile("s_barrier" ::: "memory")

// ---------- weight transpose + convert: W (1024x1024 fp32, KxN) -> WT (NxK bf16) ----------
__global__ __launch_bounds__(256) void wtrans_kernel(
    const float* __restrict__ W0, const float* __restrict__ W1,
    const float* __restrict__ W2, const float* __restrict__ W3,
    unsigned short* __restrict__ T0, unsigned short* __restrict__ T1,
    unsigned short* __restrict__ T2, unsigned short* __restrict__ T3) {
  const float* W = blockIdx.z == 0 ? W0 : blockIdx.z == 1 ? W1 : blockIdx.z == 2 ? W2 : W3;
  unsigned short* T = blockIdx.z == 0 ? T0 : blockIdx.z == 1 ? T1 : blockIdx.z == 2 ? T2 : T3;
  __shared__ float tile[32][33];
  const int tx = threadIdx.x & 31, ty = threadIdx.x >> 5;
  const int n0 = blockIdx.x * 32, k0 = blockIdx.y * 32;
#pragma unroll
  for (int i = 0; i < 4; ++i)
    tile[ty + 8 * i][tx] = W[(size_t)(k0 + ty + 8 * i) * D_MODEL + n0 + tx];
  __syncthreads();
#pragma unroll
  for (int i = 0; i < 4; ++i)
    T[(size_t)(n0 + ty + 8 * i) * D_MODEL + k0 + tx] = f2bf(tile[tx][ty + 8 * i]);
}

#define MFMA16(p, A00, A01, A10, A11)                                                        \
  _Pragma("unroll") for (int n = 0; n < 4; ++n) {                                            \
    acc[2*(p)][n]   = __builtin_amdgcn_mfma_f32_16x16x32_bf16(A00, bfr[n][0], acc[2*(p)][n], 0, 0, 0);   \
    acc[2*(p)][n]   = __builtin_amdgcn_mfma_f32_16x16x32_bf16(A01, bfr[n][1], acc[2*(p)][n], 0, 0, 0);   \
    acc[2*(p)+1][n] = __builtin_amdgcn_mfma_f32_16x16x32_bf16(A10, bfr[n][0], acc[2*(p)+1][n], 0, 0, 0); \
    acc[2*(p)+1][n] = __builtin_amdgcn_mfma_f32_16x16x32_bf16(A11, bfr[n][1], acc[2*(p)+1][n], 0, 0, 0); \
  }

#define LDA_(Ac, m, ksoff) (*(const s16x8*)((Ac) + (wm * 128 + (m) * 16 + lrow) * 128 + (ksoff)))
#define LDB_(Bc, n, ksoff) (*(const s16x8*)((Bc) + (wn * 64 + (n) * 16 + lrow) * 128 + (ksoff)))

// =====================================================================================
// qkv fused kernel: 8 compute waves (R2-proven schedule, B-only vmcnt(4) ledger) +
// 4 producer waves (fp32 A -> cvt_pk -> swizzled ds_write, per-wave private vmcnt).
// A triple-buffered (3x32KB), B double-buffered (2x32KB) = 160KB LDS.
// R8 lesson: __launch_bounds__(768,3) capped VGPR at 84 -> S0/S1 (128 VGPR) spilled to
// scratch (WRITE_SIZE 1.05GB, MfmaUtil 12%). Plain __launch_bounds__(768) frees the
// allocator; 12 waves/block @160KB LDS is 1 block/CU either way (3 waves/SIMD).
// =====================================================================================

// producer: load 8 row-chunks of A(u+2) into set S (k0 half)
#define PLOAD(S, u, k0)                                                                   \
  _Pragma("unroll") for (int k = (k0); k < (k0) + 8; ++k)                                 \
    S[k] = *(const f32x4*)(Abase + (size_t)(16 * k) * D_MODEL + (size_t)(u) * BK);

// producer: cvt + swizzled ds_write of 8 chunks from set S into LDS buffer `dst`
#define PWRITE(S, dst, k0)                                                                \
  _Pragma("unroll") for (int k = (k0); k < (k0) + 8; ++k) {                               \
    const int r = pr + 16 * k;                                                            \
    u32x2 wv;                                                                             \
    wv[0] = cvtpk_bf16(S[k][0], S[k][1]);                                                 \
    wv[1] = cvtpk_bf16(S[k][2], S[k][3]);                                                 \
    *(u32x2*)((dst) + (r >> 7) * 16384 + (r & 127) * 128 +                                \
              (((pc >> 1) ^ (r & 7)) * 16) + (pc & 1) * 8) = wv;                          \
  }

// one producer tile: loads A(u+2)->SL, writes A(u+1)<-SW into Pnxt; 8 barriers
#define PROD_TILE(u, SL, SW)                                                              \
  {                                                                                       \
    const bool ld = ((u) + 2 < NT);                                                       \
    const bool wr = ((u) + 1 < NT);                                                       \
    if (ld) { PLOAD(SL, (u) + 2, 0) }                                                     \
    BAR(); BAR();                                                                         \
    if (ld) { PLOAD(SL, (u) + 2, 8) }                                                     \
    BAR(); BAR();                                                                         \
    if (wr) { PWRITE(SW, Pnxt, 0) }                                                       \
    BAR(); BAR();                                                                         \
    if (wr) { PWRITE(SW, Pnxt, 8) }                                                       \
    BAR();                                                                                \
    asm volatile("s_waitcnt lgkmcnt(0)" ::: "memory");                                    \
    BAR();                                                                                \
    char* t_ = Pcur; Pcur = Pnxt; Pnxt = Ppf; Ppf = t_;                                   \
  }

__global__ __launch_bounds__(768) void qkv_gemm8p(
    const float* __restrict__ Xq, const float* __restrict__ Xk, const float* __restrict__ Xv,
    const unsigned short* __restrict__ WqT, const unsigned short* __restrict__ WkT,
    const unsigned short* __restrict__ WvT,
    const float* __restrict__ bq, const float* __restrict__ bk, const float* __restrict__ bv,
    unsigned short* __restrict__ Qb, unsigned short* __restrict__ Kb,
    unsigned short* __restrict__ Vb) {
  extern __shared__ char smem[];
  const int z = blockIdx.z;
  const float* A32 = z == 0 ? Xq : z == 1 ? Xk : Xv;
  const unsigned short* BT = z == 0 ? WqT : z == 1 ? WkT : WvT;
  const float* bias = z == 0 ? bq : z == 1 ? bk : bv;
  unsigned short* C = z == 0 ? Qb : z == 1 ? Kb : Vb;

  const int tid = threadIdx.x;
  const int id = blockIdx.y * gridDim.x + blockIdx.x;  // 0..511
  const int sw = (id & 7) * 64 + (id >> 3);            // bijective XCD swizzle (512%8==0)
  const int mbase = (sw >> 2) * 256;
  const int nbase = (sw & 3) * 256;

  if (tid < 512) {
    // ================= compute path (R2-proven schedule; A staged by producers) ========
    const int lane = tid & 63, wid = tid >> 6;
    const int wm = wid >> 2, wn = wid & 3;
    const int lrow = lane & 15, lkg = lane >> 4;
    const int sgoff = (((tid & 7) ^ ((tid >> 3) & 7)) * 8);
    const int srow = tid >> 3;
    const int soff0 = ((0 + lkg) ^ (lrow & 7)) * 16;
    const int soff1 = ((4 + lkg) ^ (lrow & 7)) * 16;
    const int ldsw = wid * 1024;

    auto stB = [&](char* dst, int u, int half) {
      const unsigned short* G =
          BT + (size_t)(nbase + half * 128 + srow) * D_MODEL + u * BK + sgoff;
      char* L = dst + half * 16384 + ldsw;
      gload_lds16(G, L);
      gload_lds16(G + (size_t)64 * D_MODEL, L + 8192);
    };

    f32x4 acc[8][4];
    f32x4 zero = {0.f, 0.f, 0.f, 0.f};
#pragma unroll
    for (int m = 0; m < 8; ++m)
#pragma unroll
      for (int n = 0; n < 4; ++n) acc[m][n] = zero;
    s16x8 bfr[4][2];

    char* Acur = smem;            // A(u)   = buffer u%3
    char* Anxt = smem + 32768;
    char* Apf  = smem + 65536;
    char* Bcur = smem + 98304;
    char* Bnxt = smem + 131072;

    // prologue: B(0),B(1) staged; vmcnt(4) keeps B(1) in flight. A(0) by producers.
    stB(Bcur, 0, 0); stB(Bcur, 0, 1);
    stB(Bnxt, 1, 0); stB(Bnxt, 1, 1);
    asm volatile("s_waitcnt vmcnt(4)" ::: "memory");
    BAR();

#pragma unroll 1
    for (int u = 0; u < NT; ++u) {
      const bool pf = (u + 2 < NT);
      // ---- phase 0 ----
      {
        s16x8 a00 = LDA_(Acur, 0, soff0), a01 = LDA_(Acur, 0, soff1);
        s16x8 a10 = LDA_(Acur, 1, soff0), a11 = LDA_(Acur, 1, soff1);
#pragma unroll
        for (int n = 0; n < 4; ++n) { bfr[n][0] = LDB_(Bcur, n, soff0); bfr[n][1] = LDB_(Bcur, n, soff1); }
        BAR();
        __builtin_amdgcn_s_setprio(1);
        MFMA16(0, a00, a01, a10, a11);
        __builtin_amdgcn_s_setprio(0);
        BAR();
      }
      // ---- phase 1 ----
      {
        s16x8 a00 = LDA_(Acur, 2, soff0), a01 = LDA_(Acur, 2, soff1);
        s16x8 a10 = LDA_(Acur, 3, soff0), a11 = LDA_(Acur, 3, soff1);
        BAR();
        __builtin_amdgcn_s_setprio(1);
        MFMA16(1, a00, a01, a10, a11);
        __builtin_amdgcn_s_setprio(0);
        BAR();
      }
      // ---- phase 2: stage B(u+2) lo -> Bcur (reads done at ph0) ----
      {
        s16x8 a00 = LDA_(Acur, 4, soff0), a01 = LDA_(Acur, 4, soff1);
        s16x8 a10 = LDA_(Acur, 5, soff0), a11 = LDA_(Acur, 5, soff1);
        if (pf) stB(Bcur, u + 2, 0);
        BAR();
        __builtin_amdgcn_s_setprio(1);
        MFMA16(2, a00, a01, a10, a11);
        __builtin_amdgcn_s_setprio(0);
        BAR();
      }
      // ---- phase 3: stage B(u+2) hi; counted vmcnt(4) (B-only ledger) ----
      {
        s16x8 a00 = LDA_(Acur, 6, soff0), a01 = LDA_(Acur, 6, soff1);
        s16x8 a10 = LDA_(Acur, 7, soff0), a11 = LDA_(Acur, 7, soff1);
        if (pf) {
          stB(Bcur, u + 2, 1);
          asm volatile("s_waitcnt vmcnt(4)" ::: "memory");  // keep B(u+2); drain B(u+1)
        } else {
          asm volatile("s_waitcnt vmcnt(0)" ::: "memory");
        }
        BAR();
        __builtin_amdgcn_s_setprio(1);
        MFMA16(3, a00, a01, a10, a11);
        __builtin_amdgcn_s_setprio(0);
        BAR();
      }
      // rotate (register moves only — rule #20)
      char* t = Acur; Acur = Anxt; Anxt = Apf; Apf = t;
      char* tb = Bcur; Bcur = Bnxt; Bnxt = tb;
    }

    // ---- epilogue: C layout col=lane&15, row=(lane>>4)*4+r (m89-verified) ----
    const size_t crow0 = mbase + wm * 128;
    const int ccol0 = nbase + wn * 64;
#pragma unroll
    for (int m = 0; m < 8; ++m) {
#pragma unroll
      for (int n = 0; n < 4; ++n) {
        const int col = ccol0 + n * 16 + lrow;
        const float bv = bias[col];
#pragma unroll
        for (int r = 0; r < 4; ++r) {
          const size_t row = crow0 + m * 16 + lkg * 4 + r;
          C[row * D_MODEL + col] = f2bf(acc[m][n][r] + bv);
        }
      }
    }
  } else {
    // ================= producer path (4 waves, fp32 A -> bf16 LDS) =====================
    const int pt = tid - 512;      // 0..255
    const int pr = pt >> 4;        // base row 0..15 (handles rows pr+16k)
    const int pc = pt & 15;        // 16B fp32 chunk within the 64-col row (0..15)
    const float* Abase = A32 + (size_t)(mbase + pr) * D_MODEL + pc * 4;

    char* Pcur = smem;             // buffer u%3   (at tile u)
    char* Pnxt = smem + 32768;     // buffer (u+1)%3 — producer write target
    char* Ppf  = smem + 65536;

    f32x4 S0[16], S1[16];

    // prologue: A(0) -> S0 -> LDS buf0; A(1) -> S1 (written during tile 0)
    PLOAD(S0, 0, 0) PLOAD(S0, 0, 8)
    PWRITE(S0, Pcur, 0) PWRITE(S0, Pcur, 8)   // data-dep drains S0 loads (own-wave vmcnt)
    PLOAD(S1, 1, 0) PLOAD(S1, 1, 8)
    asm volatile("s_waitcnt lgkmcnt(0)" ::: "memory");
    BAR();

#pragma unroll 1
    for (int uu = 0; uu < NT; uu += 2) {
      PROD_TILE(uu, S0, S1)       // load A(uu+2)->S0, write A(uu+1)<-S1
      PROD_TILE(uu + 1, S1, S0)   // load A(uu+3)->S1, write A(uu+2)<-S0
    }
    // no epilogue for producers
  }
}

// =====================================================================================
// out_gemm8: R7-proven bf16 path (A+B via gload_lds, triple-A rotation, vmcnt(8))
// =====================================================================================
__global__ __launch_bounds__(512, 1) void out_gemm8(
    const unsigned short* __restrict__ A, const unsigned short* __restrict__ BT,
    const float* __restrict__ bias, float* __restrict__ Cp) {
  extern __shared__ char smem[];
  const int tid = threadIdx.x;
  const int lane = tid & 63, wid = tid >> 6;
  const int wm = wid >> 2, wn = wid & 3;
  const int lrow = lane & 15, lkg = lane >> 4;

  const int id = blockIdx.y * gridDim.x + blockIdx.x;
  const int sw = (id & 7) * 64 + (id >> 3);
  const int mbase = (sw >> 2) * 256;
  const int nbase = (sw & 3) * 256;

  const int sgoff = (((tid & 7) ^ ((tid >> 3) & 7)) * 8);
  const int srow = tid >> 3;
  const int soff0 = ((0 + lkg) ^ (lrow & 7)) * 16;
  const int soff1 = ((4 + lkg) ^ (lrow & 7)) * 16;
  const int ldsw = wid * 1024;

  auto stA = [&](char* dst, int u, int half) {
    const unsigned short* G =
        A + (size_t)(mbase + half * 128 + srow) * D_MODEL + u * BK + sgoff;
    char* L = dst + half * 16384 + ldsw;
    gload_lds16(G, L);
    gload_lds16(G + (size_t)64 * D_MODEL, L + 8192);
  };
  auto stB = [&](char* dst, int u, int half) {
    const unsigned short* G =
        BT + (size_t)(nbase + half * 128 + srow) * D_MODEL + u * BK + sgoff;
    char* L = dst + half * 16384 + ldsw;
    gload_lds16(G, L);
    gload_lds16(G + (size_t)64 * D_MODEL, L + 8192);
  };

  f32x4 acc[8][4];
  f32x4 zero = {0.f, 0.f, 0.f, 0.f};
#pragma unroll
  for (int m = 0; m < 8; ++m)
#pragma unroll
    for (int n = 0; n < 4; ++n) acc[m][n] = zero;
  s16x8 bfr[4][2];

  char* Acur = smem;
  char* Anxt = smem + 32768;
  char* Apf  = smem + 65536;
  char* Bcur = smem + 98304;
  char* Bnxt = smem + 131072;

  stA(Acur, 0, 0); stA(Acur, 0, 1); stB(Bcur, 0, 0); stB(Bcur, 0, 1);
  stA(Anxt, 1, 0); stA(Anxt, 1, 1); stB(Bnxt, 1, 0); stB(Bnxt, 1, 1);
  asm volatile("s_waitcnt vmcnt(8)" ::: "memory");
  BAR();

#pragma unroll 1
  for (int u = 0; u < NT; ++u) {
    const bool pf = (u + 2 < NT);
    {
      s16x8 a00 = LDA_(Acur, 0, soff0), a01 = LDA_(Acur, 0, soff1);
      s16x8 a10 = LDA_(Acur, 1, soff0), a11 = LDA_(Acur, 1, soff1);
#pragma unroll
      for (int n = 0; n < 4; ++n) { bfr[n][0] = LDB_(Bcur, n, soff0); bfr[n][1] = LDB_(Bcur, n, soff1); }
      if (pf) stA(Apf, u + 2, 0);
      BAR();
      __builtin_amdgcn_s_setprio(1);
      MFMA16(0, a00, a01, a10, a11);
      __builtin_amdgcn_s_setprio(0);
      BAR();
    }
    {
      s16x8 a00 = LDA_(Acur, 2, soff0), a01 = LDA_(Acur, 2, soff1);
      s16x8 a10 = LDA_(Acur, 3, soff0), a11 = LDA_(Acur, 3, soff1);
      if (pf) stA(Apf, u + 2, 1);
      BAR();
      __builtin_amdgcn_s_setprio(1);
      MFMA16(1, a00, a01, a10, a11);
      __builtin_amdgcn_s_setprio(0);
      BAR();
    }
    {
      s16x8 a00 = LDA_(Acur, 4, soff0), a01 = LDA_(Acur, 4, soff1);
      s16x8 a10 = LDA_(Acur, 5, soff0), a11 = LDA_(Acur, 5, soff1);
      if (pf) stB(Bcur, u + 2, 0);
      BAR();
      __builtin_amdgcn_s_setprio(1);
      MFMA16(2, a00, a01, a10, a11);
      __builtin_amdgcn_s_setprio(0);
      BAR();
    }
    {
      s16x8 a00 = LDA_(Acur, 6, soff0), a01 = LDA_(Acur, 6, soff1);
      s16x8 a10 = LDA_(Acur, 7, soff0), a11 = LDA_(Acur, 7, soff1);
      if (pf) {
        stB(Bcur, u + 2, 1);
        asm volatile("s_waitcnt vmcnt(8)" ::: "memory");
      } else {
        asm volatile("s_waitcnt vmcnt(0)" ::: "memory");
      }
      BAR();
      __builtin_amdgcn_s_setprio(1);
      MFMA16(3, a00, a01, a10, a11);
      __builtin_amdgcn_s_setprio(0);
      BAR();
    }
    char* t = Acur; Acur = Anxt; Anxt = Apf; Apf = t;
    char* tb = Bcur; Bcur = Bnxt; Bnxt = tb;
  }

  const size_t crow0 = mbase + wm * 128;
  const int ccol0 = nbase + wn * 64;
#pragma unroll
  for (int m = 0; m < 8; ++m) {
#pragma unroll
    for (int n = 0; n < 4; ++n) {
      const int col = ccol0 + n * 16 + lrow;
      const float bv = bias[col];
#pragma unroll
      for (int r = 0; r < 4; ++r) {
        const size_t row = crow0 + m * 16 + lkg * 4 + r;
        Cp[row * D_MODEL + col] = acc[m][n][r] + bv;
      }
    }
  }
}

// ---------- per-row 16-head attention: one wave per batch row ----------
__global__ __launch_bounds__(256) void attn_kernel(
    const unsigned short* __restrict__ Qb, const unsigned short* __restrict__ Kb,
    const unsigned short* __restrict__ Vb, unsigned short* __restrict__ Ob) {
  __shared__ __align__(16) unsigned short sm[4][3][16 * 72];
  const int tid = threadIdx.x, lane = tid & 63, wid = tid >> 6;
  const size_t row = (size_t)blockIdx.x * 4 + wid;
  const unsigned short* srcs[3] = {Qb + row * 1024, Kb + row * 1024, Vb + row * 1024};
#pragma unroll
  for (int m = 0; m < 3; ++m) {
#pragma unroll
    for (int i = 0; i < 2; ++i) {
      int c = lane * 2 + i;
      int h = c >> 3, col = (c & 7) * 8;
      *(u16x8*)&sm[wid][m][h * 72 + col] = *(const u16x8*)(srcs[m] + h * 64 + col);
    }
  }
  __syncthreads();

  const int h = lane & 15, gq = lane >> 4;
  float s[4] = {0.f, 0.f, 0.f, 0.f};
#pragma unroll
  for (int dc = 0; dc < 8; ++dc) {
    u16x8 qv = *(const u16x8*)&sm[wid][0][h * 72 + dc * 8];
    float qf[8];
#pragma unroll
    for (int e = 0; e < 8; ++e) qf[e] = bf2f(qv[e]);
#pragma unroll
    for (int j = 0; j < 4; ++j) {
      u16x8 kv = *(const u16x8*)&sm[wid][1][(gq * 4 + j) * 72 + dc * 8];
#pragma unroll
      for (int e = 0; e < 8; ++e) s[j] += qf[e] * bf2f(kv[e]);
    }
  }
  float mx = s[0];
#pragma unroll
  for (int j = 0; j < 4; ++j) { s[j] *= 0.125f; mx = fmaxf(mx * (j == 0 ? 0.125f : 1.f), s[j]); }
  mx = fmaxf(mx, __shfl_xor(mx, 16, 64));
  mx = fmaxf(mx, __shfl_xor(mx, 32, 64));
  float p[4], sum = 0.f;
#pragma unroll
  for (int j = 0; j < 4; ++j) { p[j] = __expf(s[j] - mx); sum += p[j]; }
  sum += __shfl_xor(sum, 16, 64);
  sum += __shfl_xor(sum, 32, 64);
  const float rinv = 1.0f / sum;
  float pall[16];
#pragma unroll
  for (int t = 0; t < 4; ++t)
#pragma unroll
    for (int j = 0; j < 4; ++j) pall[t * 4 + j] = __shfl(p[j], h + 16 * t, 64);
  float o[16];
#pragma unroll
  for (int e = 0; e < 16; ++e) o[e] = 0.f;
  const int db = gq * 16;
#pragma unroll
  for (int g = 0; g < 16; ++g) {
    float pg = pall[g];
    u16x8 v0 = *(const u16x8*)&sm[wid][2][g * 72 + db];
    u16x8 v1 = *(const u16x8*)&sm[wid][2][g * 72 + db + 8];
#pragma unroll
    for (int e = 0; e < 8; ++e) { o[e] += pg * bf2f(v0[e]); o[8 + e] += pg * bf2f(v1[e]); }
  }
  u16x8 r0, r1;
#pragma unroll
  for (int e = 0; e < 8; ++e) { r0[e] = f2bf(o[e] * rinv); r1[e] = f2bf(o[8 + e] * rinv); }
  unsigned short* dst = Ob + row * 1024 + h * 64 + db;
  *(u16x8*)dst = r0;
  *(u16x8*)(dst + 8) = r1;
}

extern "C" void kernel_launch(void* const* d_in, const int* in_sizes, int n_in,
                              void* d_out, int out_size, void* d_ws, size_t ws_size,
                              hipStream_t stream) {
  const float* queries = (const float*)d_in[0];
  const float* keys    = (const float*)d_in[1];
  const float* values  = (const float*)d_in[2];
  const float* Wq = (const float*)d_in[3];
  const float* bq = (const float*)d_in[4];
  const float* Wk = (const float*)d_in[5];
  const float* bk = (const float*)d_in[6];
  const float* Wv = (const float*)d_in[7];
  const float* bv = (const float*)d_in[8];
  const float* Wo = (const float*)d_in[9];
  const float* bo = (const float*)d_in[10];
  float* out = (float*)d_out;

  unsigned short* ws = (unsigned short*)d_ws;
  const size_t WE = (size_t)1024 * 1024;
  const size_t XE = (size_t)NROWS * 1024;
  unsigned short* WqT = ws;
  unsigned short* WkT = WqT + WE;
  unsigned short* WvT = WkT + WE;
  unsigned short* WoT = WvT + WE;
  unsigned short* Qb  = WoT + WE;
  unsigned short* Kb  = Qb + XE;
  unsigned short* Vb  = Kb + XE;
  unsigned short* Ob  = Vb + XE;
  // ws use: 8 MB weights + 4 x 64 MB = 264 MB

  hipFuncSetAttribute((const void*)qkv_gemm8p, hipFuncAttributeMaxDynamicSharedMemorySize, 163840);
  hipFuncSetAttribute((const void*)out_gemm8, hipFuncAttributeMaxDynamicSharedMemorySize, 163840);

  wtrans_kernel<<<dim3(32, 32, 4), 256, 0, stream>>>(Wq, Wk, Wv, Wo, WqT, WkT, WvT, WoT);
  qkv_gemm8p<<<dim3(4, 128, 3), 768, 163840, stream>>>(
      queries, keys, values, WqT, WkT, WvT, bq, bk, bv, Qb, Kb, Vb);
  attn_kernel<<<dim3(NROWS / 4), 256, 0, stream>>>(Qb, Kb, Vb, Ob);
  out_gemm8<<<dim3(4, 128, 1), 512, 163840, stream>>>(Ob, WoT, bo, out);
}

// Round 10
// 795.358 us; speedup vs baseline: 1.0309x; 1.0275x over previous
//
#include <hip/hip_runtime.h>

typedef __attribute__((ext_vector_type(8))) unsigned short u16x8;
typedef __attribute__((ext_vector_type(8))) short s16x8;
typedef __attribute__((ext_vector_type(4))) float f32x4;
typedef __attribute__((ext_vector_type(2))) unsigned int u32x2;

#define D_MODEL 1024
#define NROWS 32768
#define BK 64
#define NT 16  // K-tiles = 1024/64

__device__ __forceinline__ unsigned short f2bf(float f) {
  union { float f; unsigned int u; } c; c.f = f;
  return (unsigned short)((c.u + 0x7fffu + ((c.u >> 16) & 1u)) >> 16);
}
__device__ __forceinline__ float bf2f(unsigned short h) {
  union { unsigned int u; float f; } c; c.u = ((unsigned int)h) << 16;
  return c.f;
}
// packed fp32 pair -> 2x bf16 (RTNE); lo -> low 16b, hi -> high 16b (HW-verified in R5)
__device__ __forceinline__ unsigned int cvtpk_bf16(float lo, float hi) {
  unsigned int r;
  asm("v_cvt_pk_bf16_f32 %0, %1, %2" : "=v"(r) : "v"(lo), "v"(hi));
  return r;
}

// async global->LDS, 16B per lane; lds dest is wave-uniform base (+lane*16 implicit)
__device__ __forceinline__ void gload_lds16(const void* gsrc, void* ldst) {
  const __attribute__((address_space(1))) void* g =
      reinterpret_cast<const __attribute__((address_space(1))) void*>(
          reinterpret_cast<unsigned long long>(gsrc));
  __attribute__((address_space(3))) void* l =
      reinterpret_cast<__attribute__((address_space(3))) void*>(
          static_cast<unsigned int>(reinterpret_cast<unsigned long long>(ldst)));
  __builtin_amdgcn_global_load_lds(g, l, 16, 0, 0);
}

#define BAR() asm volatile("s_barrier" ::: "memory")

// ---------- weight transpose + convert: W (1024x1024 fp32, KxN) -> WT (NxK bf16) ----------
__global__ __launch_bounds__(256) void wtrans_kernel(
    const float* __restrict__ W0, const float* __restrict__ W1,
    const float* __restrict__ W2, const float* __restrict__ W3,
    unsigned short* __restrict__ T0, unsigned short* __restrict__ T1,
    unsigned short* __restrict__ T2, unsigned short* __restrict__ T3) {
  const float* W = blockIdx.z == 0 ? W0 : blockIdx.z == 1 ? W1 : blockIdx.z == 2 ? W2 : W3;
  unsigned short* T = blockIdx.z == 0 ? T0 : blockIdx.z == 1 ? T1 : blockIdx.z == 2 ? T2 : T3;
  __shared__ float tile[32][33];
  const int tx = threadIdx.x & 31, ty = threadIdx.x >> 5;
  const int n0 = blockIdx.x * 32, k0 = blockIdx.y * 32;
#pragma unroll
  for (int i = 0; i < 4; ++i)
    tile[ty + 8 * i][tx] = W[(size_t)(k0 + ty + 8 * i) * D_MODEL + n0 + tx];
  __syncthreads();
#pragma unroll
  for (int i = 0; i < 4; ++i)
    T[(size_t)(n0 + ty + 8 * i) * D_MODEL + k0 + tx] = f2bf(tile[tx][ty + 8 * i]);
}

#define MFMA16(p, A00, A01, A10, A11)                                                        \
  _Pragma("unroll") for (int n = 0; n < 4; ++n) {                                            \
    acc[2*(p)][n]   = __builtin_amdgcn_mfma_f32_16x16x32_bf16(A00, bfr[n][0], acc[2*(p)][n], 0, 0, 0);   \
    acc[2*(p)][n]   = __builtin_amdgcn_mfma_f32_16x16x32_bf16(A01, bfr[n][1], acc[2*(p)][n], 0, 0, 0);   \
    acc[2*(p)+1][n] = __builtin_amdgcn_mfma_f32_16x16x32_bf16(A10, bfr[n][0], acc[2*(p)+1][n], 0, 0, 0); \
    acc[2*(p)+1][n] = __builtin_amdgcn_mfma_f32_16x16x32_bf16(A11, bfr[n][1], acc[2*(p)+1][n], 0, 0, 0); \
  }

#define LDA_(Ac, m, ksoff) (*(const s16x8*)((Ac) + (wm * 128 + (m) * 16 + lrow) * 128 + (ksoff)))
#define LDB_(Bc, n, ksoff) (*(const s16x8*)((Bc) + (wn * 64 + (n) * 16 + lrow) * 128 + (ksoff)))

// =====================================================================================
// qkv fused kernel: 8 compute waves (R2-proven schedule, B-only vmcnt(4) ledger) +
// 4 producer waves (fp32 A -> cvt_pk -> swizzled ds_write, per-wave private vmcnt).
// A triple-buffered (3x32KB), B double-buffered (2x32KB) = 160KB LDS.
// R8/R9 lesson: with extern __shared__ the compiler can't see 160KB LDS, its occupancy
// heuristic targets ~24 waves/CU and caps arch-VGPRs at 84 -> producer S0/S1 (128
// VGPRs; global_load can't target AGPRs) spill to scratch (WRITE_SIZE 1.05GB).
// amdgpu_waves_per_eu(3,3) pins the target at the TRUE LDS-bound occupancy
// (12 waves/block = 3/SIMD, 1 block/CU) -> ~682-reg budget, no spill.
// =====================================================================================

// producer: load 8 row-chunks of A(u+2) into set S (k0 half)
#define PLOAD(S, u, k0)                                                                   \
  _Pragma("unroll") for (int k = (k0); k < (k0) + 8; ++k)                                 \
    S[k] = *(const f32x4*)(Abase + (size_t)(16 * k) * D_MODEL + (size_t)(u) * BK);

// producer: cvt + swizzled ds_write of 8 chunks from set S into LDS buffer `dst`
#define PWRITE(S, dst, k0)                                                                \
  _Pragma("unroll") for (int k = (k0); k < (k0) + 8; ++k) {                               \
    const int r = pr + 16 * k;                                                            \
    u32x2 wv;                                                                             \
    wv[0] = cvtpk_bf16(S[k][0], S[k][1]);                                                 \
    wv[1] = cvtpk_bf16(S[k][2], S[k][3]);                                                 \
    *(u32x2*)((dst) + (r >> 7) * 16384 + (r & 127) * 128 +                                \
              (((pc >> 1) ^ (r & 7)) * 16) + (pc & 1) * 8) = wv;                          \
  }

// one producer tile: loads A(u+2)->SL, writes A(u+1)<-SW into Pnxt; 8 barriers
#define PROD_TILE(u, SL, SW)                                                              \
  {                                                                                       \
    const bool ld = ((u) + 2 < NT);                                                       \
    const bool wr = ((u) + 1 < NT);                                                       \
    if (ld) { PLOAD(SL, (u) + 2, 0) }                                                     \
    BAR(); BAR();                                                                         \
    if (ld) { PLOAD(SL, (u) + 2, 8) }                                                     \
    BAR(); BAR();                                                                         \
    if (wr) { PWRITE(SW, Pnxt, 0) }                                                       \
    BAR(); BAR();                                                                         \
    if (wr) { PWRITE(SW, Pnxt, 8) }                                                       \
    BAR();                                                                                \
    asm volatile("s_waitcnt lgkmcnt(0)" ::: "memory");                                    \
    BAR();                                                                                \
    char* t_ = Pcur; Pcur = Pnxt; Pnxt = Ppf; Ppf = t_;                                   \
  }

__global__ __launch_bounds__(768)
__attribute__((amdgpu_waves_per_eu(3, 3)))
void qkv_gemm8p(
    const float* __restrict__ Xq, const float* __restrict__ Xk, const float* __restrict__ Xv,
    const unsigned short* __restrict__ WqT, const unsigned short* __restrict__ WkT,
    const unsigned short* __restrict__ WvT,
    const float* __restrict__ bq, const float* __restrict__ bk, const float* __restrict__ bv,
    unsigned short* __restrict__ Qb, unsigned short* __restrict__ Kb,
    unsigned short* __restrict__ Vb) {
  extern __shared__ char smem[];
  const int z = blockIdx.z;
  const float* A32 = z == 0 ? Xq : z == 1 ? Xk : Xv;
  const unsigned short* BT = z == 0 ? WqT : z == 1 ? WkT : WvT;
  const float* bias = z == 0 ? bq : z == 1 ? bk : bv;
  unsigned short* C = z == 0 ? Qb : z == 1 ? Kb : Vb;

  const int tid = threadIdx.x;
  const int id = blockIdx.y * gridDim.x + blockIdx.x;  // 0..511
  const int sw = (id & 7) * 64 + (id >> 3);            // bijective XCD swizzle (512%8==0)
  const int mbase = (sw >> 2) * 256;
  const int nbase = (sw & 3) * 256;

  if (tid < 512) {
    // ================= compute path (R2-proven schedule; A staged by producers) ========
    const int lane = tid & 63, wid = tid >> 6;
    const int wm = wid >> 2, wn = wid & 3;
    const int lrow = lane & 15, lkg = lane >> 4;
    const int sgoff = (((tid & 7) ^ ((tid >> 3) & 7)) * 8);
    const int srow = tid >> 3;
    const int soff0 = ((0 + lkg) ^ (lrow & 7)) * 16;
    const int soff1 = ((4 + lkg) ^ (lrow & 7)) * 16;
    const int ldsw = wid * 1024;

    auto stB = [&](char* dst, int u, int half) {
      const unsigned short* G =
          BT + (size_t)(nbase + half * 128 + srow) * D_MODEL + u * BK + sgoff;
      char* L = dst + half * 16384 + ldsw;
      gload_lds16(G, L);
      gload_lds16(G + (size_t)64 * D_MODEL, L + 8192);
    };

    f32x4 acc[8][4];
    f32x4 zero = {0.f, 0.f, 0.f, 0.f};
#pragma unroll
    for (int m = 0; m < 8; ++m)
#pragma unroll
      for (int n = 0; n < 4; ++n) acc[m][n] = zero;
    s16x8 bfr[4][2];

    char* Acur = smem;            // A(u)   = buffer u%3
    char* Anxt = smem + 32768;
    char* Apf  = smem + 65536;
    char* Bcur = smem + 98304;
    char* Bnxt = smem + 131072;

    // prologue: B(0),B(1) staged; vmcnt(4) keeps B(1) in flight. A(0) by producers.
    stB(Bcur, 0, 0); stB(Bcur, 0, 1);
    stB(Bnxt, 1, 0); stB(Bnxt, 1, 1);
    asm volatile("s_waitcnt vmcnt(4)" ::: "memory");
    BAR();

#pragma unroll 1
    for (int u = 0; u < NT; ++u) {
      const bool pf = (u + 2 < NT);
      // ---- phase 0 ----
      {
        s16x8 a00 = LDA_(Acur, 0, soff0), a01 = LDA_(Acur, 0, soff1);
        s16x8 a10 = LDA_(Acur, 1, soff0), a11 = LDA_(Acur, 1, soff1);
#pragma unroll
        for (int n = 0; n < 4; ++n) { bfr[n][0] = LDB_(Bcur, n, soff0); bfr[n][1] = LDB_(Bcur, n, soff1); }
        BAR();
        __builtin_amdgcn_s_setprio(1);
        MFMA16(0, a00, a01, a10, a11);
        __builtin_amdgcn_s_setprio(0);
        BAR();
      }
      // ---- phase 1 ----
      {
        s16x8 a00 = LDA_(Acur, 2, soff0), a01 = LDA_(Acur, 2, soff1);
        s16x8 a10 = LDA_(Acur, 3, soff0), a11 = LDA_(Acur, 3, soff1);
        BAR();
        __builtin_amdgcn_s_setprio(1);
        MFMA16(1, a00, a01, a10, a11);
        __builtin_amdgcn_s_setprio(0);
        BAR();
      }
      // ---- phase 2: stage B(u+2) lo -> Bcur (reads done at ph0) ----
      {
        s16x8 a00 = LDA_(Acur, 4, soff0), a01 = LDA_(Acur, 4, soff1);
        s16x8 a10 = LDA_(Acur, 5, soff0), a11 = LDA_(Acur, 5, soff1);
        if (pf) stB(Bcur, u + 2, 0);
        BAR();
        __builtin_amdgcn_s_setprio(1);
        MFMA16(2, a00, a01, a10, a11);
        __builtin_amdgcn_s_setprio(0);
        BAR();
      }
      // ---- phase 3: stage B(u+2) hi; counted vmcnt(4) (B-only ledger) ----
      {
        s16x8 a00 = LDA_(Acur, 6, soff0), a01 = LDA_(Acur, 6, soff1);
        s16x8 a10 = LDA_(Acur, 7, soff0), a11 = LDA_(Acur, 7, soff1);
        if (pf) {
          stB(Bcur, u + 2, 1);
          asm volatile("s_waitcnt vmcnt(4)" ::: "memory");  // keep B(u+2); drain B(u+1)
        } else {
          asm volatile("s_waitcnt vmcnt(0)" ::: "memory");
        }
        BAR();
        __builtin_amdgcn_s_setprio(1);
        MFMA16(3, a00, a01, a10, a11);
        __builtin_amdgcn_s_setprio(0);
        BAR();
      }
      // rotate (register moves only — rule #20)
      char* t = Acur; Acur = Anxt; Anxt = Apf; Apf = t;
      char* tb = Bcur; Bcur = Bnxt; Bnxt = tb;
    }

    // ---- epilogue: C layout col=lane&15, row=(lane>>4)*4+r (m89-verified) ----
    const size_t crow0 = mbase + wm * 128;
    const int ccol0 = nbase + wn * 64;
#pragma unroll
    for (int m = 0; m < 8; ++m) {
#pragma unroll
      for (int n = 0; n < 4; ++n) {
        const int col = ccol0 + n * 16 + lrow;
        const float bv = bias[col];
#pragma unroll
        for (int r = 0; r < 4; ++r) {
          const size_t row = crow0 + m * 16 + lkg * 4 + r;
          C[row * D_MODEL + col] = f2bf(acc[m][n][r] + bv);
        }
      }
    }
  } else {
    // ================= producer path (4 waves, fp32 A -> bf16 LDS) =====================
    const int pt = tid - 512;      // 0..255
    const int pr = pt >> 4;        // base row 0..15 (handles rows pr+16k)
    const int pc = pt & 15;        // 16B fp32 chunk within the 64-col row (0..15)
    const float* Abase = A32 + (size_t)(mbase + pr) * D_MODEL + pc * 4;

    char* Pcur = smem;             // buffer u%3   (at tile u)
    char* Pnxt = smem + 32768;     // buffer (u+1)%3 — producer write target
    char* Ppf  = smem + 65536;

    f32x4 S0[16], S1[16];

    // prologue: A(0) -> S0 -> LDS buf0; A(1) -> S1 (written during tile 0)
    PLOAD(S0, 0, 0) PLOAD(S0, 0, 8)
    PWRITE(S0, Pcur, 0) PWRITE(S0, Pcur, 8)   // data-dep drains S0 loads (own-wave vmcnt)
    PLOAD(S1, 1, 0) PLOAD(S1, 1, 8)
    asm volatile("s_waitcnt lgkmcnt(0)" ::: "memory");
    BAR();

#pragma unroll 1
    for (int uu = 0; uu < NT; uu += 2) {
      PROD_TILE(uu, S0, S1)       // load A(uu+2)->S0, write A(uu+1)<-S1
      PROD_TILE(uu + 1, S1, S0)   // load A(uu+3)->S1, write A(uu+2)<-S0
    }
    // no epilogue for producers
  }
}

// =====================================================================================
// out_gemm8: R7-proven bf16 path (A+B via gload_lds, triple-A rotation, vmcnt(8))
// =====================================================================================
__global__ __launch_bounds__(512, 1) void out_gemm8(
    const unsigned short* __restrict__ A, const unsigned short* __restrict__ BT,
    const float* __restrict__ bias, float* __restrict__ Cp) {
  extern __shared__ char smem[];
  const int tid = threadIdx.x;
  const int lane = tid & 63, wid = tid >> 6;
  const int wm = wid >> 2, wn = wid & 3;
  const int lrow = lane & 15, lkg = lane >> 4;

  const int id = blockIdx.y * gridDim.x + blockIdx.x;
  const int sw = (id & 7) * 64 + (id >> 3);
  const int mbase = (sw >> 2) * 256;
  const int nbase = (sw & 3) * 256;

  const int sgoff = (((tid & 7) ^ ((tid >> 3) & 7)) * 8);
  const int srow = tid >> 3;
  const int soff0 = ((0 + lkg) ^ (lrow & 7)) * 16;
  const int soff1 = ((4 + lkg) ^ (lrow & 7)) * 16;
  const int ldsw = wid * 1024;

  auto stA = [&](char* dst, int u, int half) {
    const unsigned short* G =
        A + (size_t)(mbase + half * 128 + srow) * D_MODEL + u * BK + sgoff;
    char* L = dst + half * 16384 + ldsw;
    gload_lds16(G, L);
    gload_lds16(G + (size_t)64 * D_MODEL, L + 8192);
  };
  auto stB = [&](char* dst, int u, int half) {
    const unsigned short* G =
        BT + (size_t)(nbase + half * 128 + srow) * D_MODEL + u * BK + sgoff;
    char* L = dst + half * 16384 + ldsw;
    gload_lds16(G, L);
    gload_lds16(G + (size_t)64 * D_MODEL, L + 8192);
  };

  f32x4 acc[8][4];
  f32x4 zero = {0.f, 0.f, 0.f, 0.f};
#pragma unroll
  for (int m = 0; m < 8; ++m)
#pragma unroll
    for (int n = 0; n < 4; ++n) acc[m][n] = zero;
  s16x8 bfr[4][2];

  char* Acur = smem;
  char* Anxt = smem + 32768;
  char* Apf  = smem + 65536;
  char* Bcur = smem + 98304;
  char* Bnxt = smem + 131072;

  stA(Acur, 0, 0); stA(Acur, 0, 1); stB(Bcur, 0, 0); stB(Bcur, 0, 1);
  stA(Anxt, 1, 0); stA(Anxt, 1, 1); stB(Bnxt, 1, 0); stB(Bnxt, 1, 1);
  asm volatile("s_waitcnt vmcnt(8)" ::: "memory");
  BAR();

#pragma unroll 1
  for (int u = 0; u < NT; ++u) {
    const bool pf = (u + 2 < NT);
    {
      s16x8 a00 = LDA_(Acur, 0, soff0), a01 = LDA_(Acur, 0, soff1);
      s16x8 a10 = LDA_(Acur, 1, soff0), a11 = LDA_(Acur, 1, soff1);
#pragma unroll
      for (int n = 0; n < 4; ++n) { bfr[n][0] = LDB_(Bcur, n, soff0); bfr[n][1] = LDB_(Bcur, n, soff1); }
      if (pf) stA(Apf, u + 2, 0);
      BAR();
      __builtin_amdgcn_s_setprio(1);
      MFMA16(0, a00, a01, a10, a11);
      __builtin_amdgcn_s_setprio(0);
      BAR();
    }
    {
      s16x8 a00 = LDA_(Acur, 2, soff0), a01 = LDA_(Acur, 2, soff1);
      s16x8 a10 = LDA_(Acur, 3, soff0), a11 = LDA_(Acur, 3, soff1);
      if (pf) stA(Apf, u + 2, 1);
      BAR();
      __builtin_amdgcn_s_setprio(1);
      MFMA16(1, a00, a01, a10, a11);
      __builtin_amdgcn_s_setprio(0);
      BAR();
    }
    {
      s16x8 a00 = LDA_(Acur, 4, soff0), a01 = LDA_(Acur, 4, soff1);
      s16x8 a10 = LDA_(Acur, 5, soff0), a11 = LDA_(Acur, 5, soff1);
      if (pf) stB(Bcur, u + 2, 0);
      BAR();
      __builtin_amdgcn_s_setprio(1);
      MFMA16(2, a00, a01, a10, a11);
      __builtin_amdgcn_s_setprio(0);
      BAR();
    }
    {
      s16x8 a00 = LDA_(Acur, 6, soff0), a01 = LDA_(Acur, 6, soff1);
      s16x8 a10 = LDA_(Acur, 7, soff0), a11 = LDA_(Acur, 7, soff1);
      if (pf) {
        stB(Bcur, u + 2, 1);
        asm volatile("s_waitcnt vmcnt(8)" ::: "memory");
      } else {
        asm volatile("s_waitcnt vmcnt(0)" ::: "memory");
      }
      BAR();
      __builtin_amdgcn_s_setprio(1);
      MFMA16(3, a00, a01, a10, a11);
      __builtin_amdgcn_s_setprio(0);
      BAR();
    }
    char* t = Acur; Acur = Anxt; Anxt = Apf; Apf = t;
    char* tb = Bcur; Bcur = Bnxt; Bnxt = tb;
  }

  const size_t crow0 = mbase + wm * 128;
  const int ccol0 = nbase + wn * 64;
#pragma unroll
  for (int m = 0; m < 8; ++m) {
#pragma unroll
    for (int n = 0; n < 4; ++n) {
      const int col = ccol0 + n * 16 + lrow;
      const float bv = bias[col];
#pragma unroll
      for (int r = 0; r < 4; ++r) {
        const size_t row = crow0 + m * 16 + lkg * 4 + r;
        Cp[row * D_MODEL + col] = acc[m][n][r] + bv;
      }
    }
  }
}

// ---------- per-row 16-head attention: one wave per batch row ----------
__global__ __launch_bounds__(256) void attn_kernel(
    const unsigned short* __restrict__ Qb, const unsigned short* __restrict__ Kb,
    const unsigned short* __restrict__ Vb, unsigned short* __restrict__ Ob) {
  __shared__ __align__(16) unsigned short sm[4][3][16 * 72];
  const int tid = threadIdx.x, lane = tid & 63, wid = tid >> 6;
  const size_t row = (size_t)blockIdx.x * 4 + wid;
  const unsigned short* srcs[3] = {Qb + row * 1024, Kb + row * 1024, Vb + row * 1024};
#pragma unroll
  for (int m = 0; m < 3; ++m) {
#pragma unroll
    for (int i = 0; i < 2; ++i) {
      int c = lane * 2 + i;
      int h = c >> 3, col = (c & 7) * 8;
      *(u16x8*)&sm[wid][m][h * 72 + col] = *(const u16x8*)(srcs[m] + h * 64 + col);
    }
  }
  __syncthreads();

  const int h = lane & 15, gq = lane >> 4;
  float s[4] = {0.f, 0.f, 0.f, 0.f};
#pragma unroll
  for (int dc = 0; dc < 8; ++dc) {
    u16x8 qv = *(const u16x8*)&sm[wid][0][h * 72 + dc * 8];
    float qf[8];
#pragma unroll
    for (int e = 0; e < 8; ++e) qf[e] = bf2f(qv[e]);
#pragma unroll
    for (int j = 0; j < 4; ++j) {
      u16x8 kv = *(const u16x8*)&sm[wid][1][(gq * 4 + j) * 72 + dc * 8];
#pragma unroll
      for (int e = 0; e < 8; ++e) s[j] += qf[e] * bf2f(kv[e]);
    }
  }
  float mx = s[0];
#pragma unroll
  for (int j = 0; j < 4; ++j) { s[j] *= 0.125f; mx = fmaxf(mx * (j == 0 ? 0.125f : 1.f), s[j]); }
  mx = fmaxf(mx, __shfl_xor(mx, 16, 64));
  mx = fmaxf(mx, __shfl_xor(mx, 32, 64));
  float p[4], sum = 0.f;
#pragma unroll
  for (int j = 0; j < 4; ++j) { p[j] = __expf(s[j] - mx); sum += p[j]; }
  sum += __shfl_xor(sum, 16, 64);
  sum += __shfl_xor(sum, 32, 64);
  const float rinv = 1.0f / sum;
  float pall[16];
#pragma unroll
  for (int t = 0; t < 4; ++t)
#pragma unroll
    for (int j = 0; j < 4; ++j) pall[t * 4 + j] = __shfl(p[j], h + 16 * t, 64);
  float o[16];
#pragma unroll
  for (int e = 0; e < 16; ++e) o[e] = 0.f;
  const int db = gq * 16;
#pragma unroll
  for (int g = 0; g < 16; ++g) {
    float pg = pall[g];
    u16x8 v0 = *(const u16x8*)&sm[wid][2][g * 72 + db];
    u16x8 v1 = *(const u16x8*)&sm[wid][2][g * 72 + db + 8];
#pragma unroll
    for (int e = 0; e < 8; ++e) { o[e] += pg * bf2f(v0[e]); o[8 + e] += pg * bf2f(v1[e]); }
  }
  u16x8 r0, r1;
#pragma unroll
  for (int e = 0; e < 8; ++e) { r0[e] = f2bf(o[e] * rinv); r1[e] = f2bf(o[8 + e] * rinv); }
  unsigned short* dst = Ob + row * 1024 + h * 64 + db;
  *(u16x8*)dst = r0;
  *(u16x8*)(dst + 8) = r1;
}

extern "C" void kernel_launch(void* const* d_in, const int* in_sizes, int n_in,
                              void* d_out, int out_size, void* d_ws, size_t ws_size,
                              hipStream_t stream) {
  const float* queries = (const float*)d_in[0];
  const float* keys    = (const float*)d_in[1];
  const float* values  = (const float*)d_in[2];
  const float* Wq = (const float*)d_in[3];
  const float* bq = (const float*)d_in[4];
  const float* Wk = (const float*)d_in[5];
  const float* bk = (const float*)d_in[6];
  const float* Wv = (const float*)d_in[7];
  const float* bv = (const float*)d_in[8];
  const float* Wo = (const float*)d_in[9];
  const float* bo = (const float*)d_in[10];
  float* out = (float*)d_out;

  unsigned short* ws = (unsigned short*)d_ws;
  const size_t WE = (size_t)1024 * 1024;
  const size_t XE = (size_t)NROWS * 1024;
  unsigned short* WqT = ws;
  unsigned short* WkT = WqT + WE;
  unsigned short* WvT = WkT + WE;
  unsigned short* WoT = WvT + WE;
  unsigned short* Qb  = WoT + WE;
  unsigned short* Kb  = Qb + XE;
  unsigned short* Vb  = Kb + XE;
  unsigned short* Ob  = Vb + XE;
  // ws use: 8 MB weights + 4 x 64 MB = 264 MB

  hipFuncSetAttribute((const void*)qkv_gemm8p, hipFuncAttributeMaxDynamicSharedMemorySize, 163840);
  hipFuncSetAttribute((const void*)out_gemm8, hipFuncAttributeMaxDynamicSharedMemorySize, 163840);

  wtrans_kernel<<<dim3(32, 32, 4), 256, 0, stream>>>(Wq, Wk, Wv, Wo, WqT, WkT, WvT, WoT);
  qkv_gemm8p<<<dim3(4, 128, 3), 768, 163840, stream>>>(
      queries, keys, values, WqT, WkT, WvT, bq, bk, bv, Qb, Kb, Vb);
  attn_kernel<<<dim3(NROWS / 4), 256, 0, stream>>>(Qb, Kb, Vb, Ob);
  out_gemm8<<<dim3(4, 128, 1), 512, 163840, stream>>>(Ob, WoT, bo, out);
}